// Round 1
// baseline (544.446 us; speedup 1.0000x reference)
//
#include <hip/hip_runtime.h>
#include <math.h>

#define N_ROWS 32768
#define DIM 64
#define KCOMP 64
#define KSPLIT 16
#define KLOCAL 4          // KCOMP / KSPLIT
#define THREADS 256
#define RPB 512           // rows per block = THREADS * 2

// ---------------- digamma (double, recurrence + asymptotic) ----------------
__device__ __forceinline__ double digamma_d(double x) {
  double r = 0.0;
  while (x < 6.0) { r -= 1.0 / x; x += 1.0; }
  double inv = 1.0 / x;
  double inv2 = inv * inv;
  double s = log(x) - 0.5 * inv
      - inv2 * (1.0/12.0 - inv2 * (1.0/120.0 - inv2 * (1.0/252.0
      - inv2 * (1.0/240.0 - inv2 * (1.0/132.0)))));
  return r + s;
}

// ---------------- prep: per-component constants + muP ----------------
// muP[k][e] = sum_d means[k][d] * P[k][d][e]
// c[k] = log_det - 0.5*D*log2pi - 0.5*D*log(dof) + 0.5*(log_lambda - D/mp) + log_w
__global__ void prep_kernel(const float* __restrict__ means,
                            const float* __restrict__ P,
                            const float* __restrict__ wc,    // [2][K]
                            const float* __restrict__ dof,   // [K]
                            const float* __restrict__ mp,    // [K]
                            float* __restrict__ muP,         // [K][DIM]
                            float* __restrict__ cvec)        // [K]
{
  int k = threadIdx.x;
  if (k >= KCOMP) return;
  const float* Pk = P + k * DIM * DIM;
  const float* mk = means + k * DIM;
  for (int e = 0; e < DIM; ++e) {
    float acc = 0.f;
    for (int d = 0; d < DIM; ++d) acc += mk[d] * Pk[d * DIM + e];
    muP[k * DIM + e] = acc;
  }
  float log_det = 0.f;
  for (int d = 0; d < DIM; ++d) log_det += logf(Pk[d * DIM + d]);

  double dofk = (double)dof[k];
  double dgsum = 0.0;
  for (int i = 0; i < DIM; ++i) dgsum += digamma_d(0.5 * (dofk - (double)i));
  double log_lambda = (double)DIM * log(2.0) + dgsum;

  // stick-breaking log weights
  double cum = 0.0;
  for (int j = 0; j < k; ++j) {
    double aj = (double)wc[j], bj = (double)wc[KCOMP + j];
    cum += digamma_d(bj) - digamma_d(aj + bj);
  }
  double ak = (double)wc[k], bk = (double)wc[KCOMP + k];
  double log_w = digamma_d(ak) - digamma_d(ak + bk) + cum;

  const double LOG2PI = 1.8378770664093454836;
  double c = (double)log_det
           - 0.5 * (double)DIM * LOG2PI
           - 0.5 * (double)DIM * log(dofk)
           + 0.5 * (log_lambda - (double)DIM / (double)mp[k])
           + log_w;
  cvec[k] = (float)c;
}

// ---------------- main: per-row per-k squared Mahalanobis + partial argmax ---
// Each thread owns 2 rows fully in registers. P is read with wave-uniform
// indices only -> compiler emits s_load (scalar pipe), v_fmac v,s,v inner loop.
__global__ __launch_bounds__(THREADS, 2) void main_kernel(
    const float* __restrict__ X,
    const float* __restrict__ P,
    const float* __restrict__ muP,
    const float* __restrict__ cvec,
    float* __restrict__ pval,   // [KSPLIT][N_ROWS]
    int*   __restrict__ pidx)   // [KSPLIT][N_ROWS]
{
  const int nb = blockIdx.x;           // 0..63
  const int ks = blockIdx.y;           // 0..15
  const int t  = threadIdx.x;
  const int r0 = nb * RPB + t;
  const int r1 = r0 + THREADS;

  // Load the two X rows into registers (fully unrolled -> stays in VGPRs).
  float x0r[DIM], x1r[DIM];
  const float4* X4 = (const float4*)X;
#pragma unroll
  for (int j = 0; j < DIM / 4; ++j) {
    float4 v0 = X4[r0 * (DIM / 4) + j];
    float4 v1 = X4[r1 * (DIM / 4) + j];
    x0r[4*j+0] = v0.x; x0r[4*j+1] = v0.y; x0r[4*j+2] = v0.z; x0r[4*j+3] = v0.w;
    x1r[4*j+0] = v1.x; x1r[4*j+1] = v1.y; x1r[4*j+2] = v1.z; x1r[4*j+3] = v1.w;
  }

  float best0 = -INFINITY, best1 = -INFINITY;
  int bi0 = 0, bi1 = 0;

  for (int kl = 0; kl < KLOCAL; ++kl) {
    const int k = ks * KLOCAL + kl;           // wave-uniform
    const float* Pk = P + k * DIM * DIM;      // uniform base
    const float* mu = muP + k * DIM;
    float sq0 = 0.f, sq1 = 0.f;

    for (int ec = 0; ec < DIM / 8; ++ec) {    // 8 e-columns at a time
      float a0[8], a1[8];
#pragma unroll
      for (int j = 0; j < 8; ++j) {
        float m = mu[ec * 8 + j];             // uniform -> s_load
        a0[j] = -m; a1[j] = -m;
      }
#pragma unroll
      for (int d = 0; d < DIM; ++d) {
        float xd0 = x0r[d];
        float xd1 = x1r[d];
#pragma unroll
        for (int j = 0; j < 8; ++j) {
          float p = Pk[d * DIM + ec * 8 + j]; // uniform -> s_load_dwordx8
          a0[j] = fmaf(xd0, p, a0[j]);
          a1[j] = fmaf(xd1, p, a1[j]);
        }
      }
#pragma unroll
      for (int j = 0; j < 8; ++j) {
        sq0 = fmaf(a0[j], a0[j], sq0);
        sq1 = fmaf(a1[j], a1[j], sq1);
      }
    }

    const float ck = cvec[k];                 // uniform
    float w0 = fmaf(-0.5f, sq0, ck);
    float w1 = fmaf(-0.5f, sq1, ck);
    if (w0 > best0) { best0 = w0; bi0 = k; }  // strict > : first-max wins
    if (w1 > best1) { best1 = w1; bi1 = k; }
  }

  pval[ks * N_ROWS + r0] = best0;  pidx[ks * N_ROWS + r0] = bi0;
  pval[ks * N_ROWS + r1] = best1;  pidx[ks * N_ROWS + r1] = bi1;
}

// ---------------- final reduce over k-splits ----------------
__global__ void reduce_kernel(const float* __restrict__ pval,
                              const int* __restrict__ pidx,
                              int* __restrict__ out)
{
  int n = blockIdx.x * blockDim.x + threadIdx.x;
  if (n >= N_ROWS) return;
  float best = -INFINITY; int bi = 0;
  for (int ks = 0; ks < KSPLIT; ++ks) {       // ascending k-splits: first-max wins
    float v = pval[ks * N_ROWS + n];
    int   i = pidx[ks * N_ROWS + n];
    if (v > best) { best = v; bi = i; }
  }
  out[n] = bi;
}

extern "C" void kernel_launch(void* const* d_in, const int* in_sizes, int n_in,
                              void* d_out, int out_size, void* d_ws, size_t ws_size,
                              hipStream_t stream) {
  const float* X     = (const float*)d_in[0];
  const float* means = (const float*)d_in[1];
  const float* P     = (const float*)d_in[2];
  const float* wc    = (const float*)d_in[3];
  const float* dof   = (const float*)d_in[4];
  const float* mp    = (const float*)d_in[5];
  int* out = (int*)d_out;

  // workspace layout (floats):
  // [0, 4096)            muP
  // [4096, 4160)         cvec
  // [8192, 8192+16N)     pval
  // [8192+16N, ...)      pidx
  float* ws   = (float*)d_ws;
  float* muP  = ws;
  float* cvec = ws + KCOMP * DIM;
  float* pval = ws + 8192;
  int*   pidx = (int*)(ws + 8192 + KSPLIT * N_ROWS);

  prep_kernel<<<1, 64, 0, stream>>>(means, P, wc, dof, mp, muP, cvec);

  dim3 grid(N_ROWS / RPB, KSPLIT);
  main_kernel<<<grid, THREADS, 0, stream>>>(X, P, muP, cvec, pval, pidx);

  reduce_kernel<<<(N_ROWS + 255) / 256, 256, 0, stream>>>(pval, pidx, out);
}

// Round 2
// 303.727 us; speedup vs baseline: 1.7926x; 1.7926x over previous
//
#include <hip/hip_runtime.h>
#include <math.h>

#define N_ROWS 32768
#define DIM 64
#define KCOMP 64
#define KSPLIT 16
#define KLOCAL 4          // KCOMP / KSPLIT
#define THREADS 256
#define RPB 512           // rows per block = THREADS * 2

#define LOG2PI_D 1.8378770664093454836

// ---------------- digamma (double, recurrence + asymptotic) ----------------
__device__ __forceinline__ double digamma_d(double x) {
  double r = 0.0;
  while (x < 6.0) { r -= 1.0 / x; x += 1.0; }
  double inv = 1.0 / x;
  double inv2 = inv * inv;
  double s = log(x) - 0.5 * inv
      - inv2 * (1.0/12.0 - inv2 * (1.0/120.0 - inv2 * (1.0/252.0
      - inv2 * (1.0/240.0 - inv2 * (1.0/132.0)))));
  return r + s;
}

// ---------------- prep1: one block per component k, one wave (64 threads) ---
// Thread i: muP[k][i]; digamma(0.5*(dof_k - i)); log(diag_i). Wave-shuffle
// reduce both sums. Lane 0 computes per-k stick-breaking terms + partial c.
__global__ void prep1_kernel(const float* __restrict__ means,
                             const float* __restrict__ P,
                             const float* __restrict__ wc,    // [2][K]
                             const float* __restrict__ dof,   // [K]
                             const float* __restrict__ mp,    // [K]
                             float*  __restrict__ muP,        // [K][DIM]
                             double* __restrict__ t_arr,      // [K] digamma(b)-digamma(a+b)
                             double* __restrict__ g_arr,      // [K] digamma(a)-digamma(a+b)
                             double* __restrict__ pc_arr)     // [K] partial constant
{
  const int k = blockIdx.x;
  const int i = threadIdx.x;            // 0..63, exactly one wave
  const float* Pk = P + k * DIM * DIM;
  const float* mk = means + k * DIM;

  // muP[k][i] = sum_d means[k][d] * P[k][d][i]
  float acc = 0.f;
#pragma unroll 8
  for (int d = 0; d < DIM; ++d) acc = fmaf(mk[d], Pk[d * DIM + i], acc);
  muP[k * DIM + i] = acc;

  // per-lane contributions to log_lambda sum and log_det sum
  double dofk = (double)dof[k];
  double s1 = digamma_d(0.5 * (dofk - (double)i));
  double s2 = log((double)Pk[i * DIM + i]);

#pragma unroll
  for (int off = 32; off > 0; off >>= 1) {
    s1 += __shfl_down(s1, off);
    s2 += __shfl_down(s2, off);
  }

  if (i == 0) {
    double ak = (double)wc[k], bk = (double)wc[KCOMP + k];
    double dgab = digamma_d(ak + bk);
    double log_lambda = (double)DIM * log(2.0) + s1;
    double pc = s2                                   // log_det
              - 0.5 * (double)DIM * LOG2PI_D
              - 0.5 * (double)DIM * log(dofk)
              + 0.5 * (log_lambda - (double)DIM / (double)mp[k]);
    t_arr[k] = digamma_d(bk) - dgab;
    g_arr[k] = digamma_d(ak) - dgab;
    pc_arr[k] = pc;
  }
}

// ---------------- prep2: stick-breaking prefix sum + final cvec ----------------
__global__ void prep2_kernel(const double* __restrict__ t_arr,
                             const double* __restrict__ g_arr,
                             const double* __restrict__ pc_arr,
                             float* __restrict__ cvec)
{
  const int k = threadIdx.x;            // 0..63
  double cum = 0.0;
  for (int j = 0; j < k; ++j) cum += t_arr[j];
  cvec[k] = (float)(pc_arr[k] + g_arr[k] + cum);
}

// ---------------- main: per-row per-k squared Mahalanobis + partial argmax ---
// Each thread owns 2 rows fully in registers. P is read with wave-uniform
// indices only -> compiler emits s_load (scalar pipe), v_fmac v,s,v inner loop.
__global__ __launch_bounds__(THREADS, 2) void main_kernel(
    const float* __restrict__ X,
    const float* __restrict__ P,
    const float* __restrict__ muP,
    const float* __restrict__ cvec,
    float* __restrict__ pval,   // [KSPLIT][N_ROWS]
    int*   __restrict__ pidx)   // [KSPLIT][N_ROWS]
{
  const int nb = blockIdx.x;           // 0..63
  const int ks = blockIdx.y;           // 0..15
  const int t  = threadIdx.x;
  const int r0 = nb * RPB + t;
  const int r1 = r0 + THREADS;

  // Load the two X rows into registers (fully unrolled -> stays in VGPRs).
  float x0r[DIM], x1r[DIM];
  const float4* X4 = (const float4*)X;
#pragma unroll
  for (int j = 0; j < DIM / 4; ++j) {
    float4 v0 = X4[r0 * (DIM / 4) + j];
    float4 v1 = X4[r1 * (DIM / 4) + j];
    x0r[4*j+0] = v0.x; x0r[4*j+1] = v0.y; x0r[4*j+2] = v0.z; x0r[4*j+3] = v0.w;
    x1r[4*j+0] = v1.x; x1r[4*j+1] = v1.y; x1r[4*j+2] = v1.z; x1r[4*j+3] = v1.w;
  }

  float best0 = -INFINITY, best1 = -INFINITY;
  int bi0 = 0, bi1 = 0;

  for (int kl = 0; kl < KLOCAL; ++kl) {
    const int k = ks * KLOCAL + kl;           // wave-uniform
    const float* Pk = P + k * DIM * DIM;      // uniform base
    const float* mu = muP + k * DIM;
    float sq0 = 0.f, sq1 = 0.f;

    for (int ec = 0; ec < DIM / 8; ++ec) {    // 8 e-columns at a time
      float a0[8], a1[8];
#pragma unroll
      for (int j = 0; j < 8; ++j) {
        float m = mu[ec * 8 + j];             // uniform -> s_load
        a0[j] = -m; a1[j] = -m;
      }
#pragma unroll
      for (int d = 0; d < DIM; ++d) {
        float xd0 = x0r[d];
        float xd1 = x1r[d];
#pragma unroll
        for (int j = 0; j < 8; ++j) {
          float p = Pk[d * DIM + ec * 8 + j]; // uniform -> s_load_dwordx8
          a0[j] = fmaf(xd0, p, a0[j]);
          a1[j] = fmaf(xd1, p, a1[j]);
        }
      }
#pragma unroll
      for (int j = 0; j < 8; ++j) {
        sq0 = fmaf(a0[j], a0[j], sq0);
        sq1 = fmaf(a1[j], a1[j], sq1);
      }
    }

    const float ck = cvec[k];                 // uniform
    float w0 = fmaf(-0.5f, sq0, ck);
    float w1 = fmaf(-0.5f, sq1, ck);
    if (w0 > best0) { best0 = w0; bi0 = k; }  // strict > : first-max wins
    if (w1 > best1) { best1 = w1; bi1 = k; }
  }

  pval[ks * N_ROWS + r0] = best0;  pidx[ks * N_ROWS + r0] = bi0;
  pval[ks * N_ROWS + r1] = best1;  pidx[ks * N_ROWS + r1] = bi1;
}

// ---------------- final reduce over k-splits ----------------
__global__ void reduce_kernel(const float* __restrict__ pval,
                              const int* __restrict__ pidx,
                              int* __restrict__ out)
{
  int n = blockIdx.x * blockDim.x + threadIdx.x;
  if (n >= N_ROWS) return;
  float best = -INFINITY; int bi = 0;
  for (int ks = 0; ks < KSPLIT; ++ks) {       // ascending k-splits: first-max wins
    float v = pval[ks * N_ROWS + n];
    int   i = pidx[ks * N_ROWS + n];
    if (v > best) { best = v; bi = i; }
  }
  out[n] = bi;
}

extern "C" void kernel_launch(void* const* d_in, const int* in_sizes, int n_in,
                              void* d_out, int out_size, void* d_ws, size_t ws_size,
                              hipStream_t stream) {
  const float* X     = (const float*)d_in[0];
  const float* means = (const float*)d_in[1];
  const float* P     = (const float*)d_in[2];
  const float* wc    = (const float*)d_in[3];
  const float* dof   = (const float*)d_in[4];
  const float* mp    = (const float*)d_in[5];
  int* out = (int*)d_out;

  // workspace layout (bytes):
  // [0, 16384)        muP   (4096 f32)
  // [16384, 16640)    cvec  (64 f32)
  // [16640, 17152)    t_arr (64 f64)
  // [17152, 17664)    g_arr (64 f64)
  // [17664, 18176)    pc_arr(64 f64)
  // [32768, ...)      pval [16][32768] f32, then pidx [16][32768] i32
  char* wsb = (char*)d_ws;
  float*  muP    = (float*)(wsb);
  float*  cvec   = (float*)(wsb + 16384);
  double* t_arr  = (double*)(wsb + 16640);
  double* g_arr  = (double*)(wsb + 17152);
  double* pc_arr = (double*)(wsb + 17664);
  float*  pval   = (float*)(wsb + 32768);
  int*    pidx   = (int*)(wsb + 32768 + KSPLIT * N_ROWS * sizeof(float));

  prep1_kernel<<<KCOMP, 64, 0, stream>>>(means, P, wc, dof, mp, muP, t_arr, g_arr, pc_arr);
  prep2_kernel<<<1, KCOMP, 0, stream>>>(t_arr, g_arr, pc_arr, cvec);

  dim3 grid(N_ROWS / RPB, KSPLIT);
  main_kernel<<<grid, THREADS, 0, stream>>>(X, P, muP, cvec, pval, pidx);

  reduce_kernel<<<(N_ROWS + 255) / 256, 256, 0, stream>>>(pval, pidx, out);
}

// Round 4
// 149.836 us; speedup vs baseline: 3.6336x; 2.0271x over previous
//
#include <hip/hip_runtime.h>
#include <math.h>

#define N_ROWS 32768
#define DIM 64
#define KCOMP 64
#define KSPLIT 4
#define KLOCAL 16          // KCOMP / KSPLIT
#define THREADS 256
#define ROWS_PER_BLOCK 128 // 4 waves * 32 rows
#define ROWS_PER_WAVE 32   // 2 row-tiles of 16

#define PT_ROW_F16 72      // 64 d + 8 pad (row stride 144 B, 16B aligned)
#define PT_ROW_BYTES 144
#define PT_SPLIT_BYTES 9216   // 64 e-rows * 144 B
#define PT_K_BYTES 18432      // hi + lo

#define LOG2PI_D 1.8378770664093454836

typedef _Float16 f16x8 __attribute__((ext_vector_type(8)));
typedef float f32x4 __attribute__((ext_vector_type(4)));

// ---------------- digamma (double, recurrence + asymptotic) ----------------
__device__ __forceinline__ double digamma_d(double x) {
  double r = 0.0;
  while (x < 6.0) { r -= 1.0 / x; x += 1.0; }
  double inv = 1.0 / x;
  double inv2 = inv * inv;
  double s = log(x) - 0.5 * inv
      - inv2 * (1.0/12.0 - inv2 * (1.0/120.0 - inv2 * (1.0/252.0
      - inv2 * (1.0/240.0 - inv2 * (1.0/132.0)))));
  return r + s;
}

// ---------------- prep1: one block per k, one wave ----------------
__global__ void prep1_kernel(const float* __restrict__ means,
                             const float* __restrict__ P,
                             const float* __restrict__ wc,
                             const float* __restrict__ dof,
                             const float* __restrict__ mp,
                             float*  __restrict__ muP,
                             double* __restrict__ t_arr,
                             double* __restrict__ g_arr,
                             double* __restrict__ pc_arr)
{
  const int k = blockIdx.x;
  const int i = threadIdx.x;            // 0..63
  const float* Pk = P + k * DIM * DIM;
  const float* mk = means + k * DIM;

  float acc = 0.f;
#pragma unroll 8
  for (int d = 0; d < DIM; ++d) acc = fmaf(mk[d], Pk[d * DIM + i], acc);
  muP[k * DIM + i] = acc;

  double dofk = (double)dof[k];
  double s1 = digamma_d(0.5 * (dofk - (double)i));
  double s2 = log((double)Pk[i * DIM + i]);
#pragma unroll
  for (int off = 32; off > 0; off >>= 1) {
    s1 += __shfl_down(s1, off);
    s2 += __shfl_down(s2, off);
  }
  if (i == 0) {
    double ak = (double)wc[k], bk = (double)wc[KCOMP + k];
    double dgab = digamma_d(ak + bk);
    double log_lambda = (double)DIM * log(2.0) + s1;
    double pc = s2
              - 0.5 * (double)DIM * LOG2PI_D
              - 0.5 * (double)DIM * log(dofk)
              + 0.5 * (log_lambda - (double)DIM / (double)mp[k]);
    t_arr[k] = digamma_d(bk) - dgab;
    g_arr[k] = digamma_d(ak) - dgab;
    pc_arr[k] = pc;
  }
}

// ---------------- prep2: stick-breaking prefix + final cvec ----------------
__global__ void prep2_kernel(const double* __restrict__ t_arr,
                             const double* __restrict__ g_arr,
                             const double* __restrict__ pc_arr,
                             float* __restrict__ cvec)
{
  const int k = threadIdx.x;
  double cum = 0.0;
  for (int j = 0; j < k; ++j) cum += t_arr[j];
  cvec[k] = (float)(pc_arr[k] + g_arr[k] + cum);
}

// ---------------- prepP: transpose + f16-split P into padded LDS image -----
// Pt[k] = [ hi: 64 e-rows x 72 f16 | lo: same ], row stride 144 B.
__global__ void prepP_kernel(const float* __restrict__ P, char* __restrict__ Pt)
{
  const int k = blockIdx.x;
  const float* Pk = P + k * DIM * DIM;
  _Float16* hi = (_Float16*)(Pt + k * PT_K_BYTES);
  _Float16* lo = (_Float16*)(Pt + k * PT_K_BYTES + PT_SPLIT_BYTES);
  for (int idx = threadIdx.x; idx < DIM * DIM; idx += THREADS) {
    int d = idx >> 6, e = idx & 63;          // coalesced read of P[k][d][e]
    float v = Pk[d * DIM + e];
    _Float16 h = (_Float16)v;
    _Float16 l = (_Float16)(v - (float)h);
    hi[e * PT_ROW_F16 + d] = h;
    lo[e * PT_ROW_F16 + d] = l;
  }
}

// ---------------- main: f16-split MFMA, fused square + argmax ----------------
__global__ __launch_bounds__(THREADS, 4) void main_kernel(
    const float* __restrict__ X,
    const char*  __restrict__ Pt,
    const float* __restrict__ muP,
    const float* __restrict__ cvec,
    float* __restrict__ pval,   // [KSPLIT][N_ROWS]
    int*   __restrict__ pidx)
{
  __shared__ uint4 lds_p4[PT_K_BYTES / 16];   // uint4 -> guaranteed 16B align
  char* lds_p = (char*)lds_p4;

  const int tid  = threadIdx.x;
  const int wave = tid >> 6;
  const int lane = tid & 63;
  const int m    = lane & 15;          // MFMA row (A) / col (B) index
  const int q    = lane >> 4;          // quad: k-slice for A/B, row-group for C
  const int ks   = blockIdx.y;
  const int rowbase = blockIdx.x * ROWS_PER_BLOCK + wave * ROWS_PER_WAVE;

  // ---- load + split X rows into register-resident A fragments ----
  // A[m=lane&15][k = q*8 + j], chain c covers d = c*32 .. c*32+31
  f16x8 ahi[2][2], alo[2][2];
#pragma unroll
  for (int rt = 0; rt < 2; ++rt) {
    int row = rowbase + rt * 16 + m;
    const float* xp = X + row * DIM;
#pragma unroll
    for (int c = 0; c < 2; ++c) {
      const float* xq = xp + c * 32 + q * 8;
      f16x8 h, l;
#pragma unroll
      for (int j = 0; j < 8; ++j) {
        float v = xq[j];
        _Float16 hv = (_Float16)v;
        h[j] = hv;
        l[j] = (_Float16)(v - (float)hv);
      }
      ahi[rt][c] = h;
      alo[rt][c] = l;
    }
  }

  float best[2][4];
  int   bidx[2][4];
#pragma unroll
  for (int rt = 0; rt < 2; ++rt)
#pragma unroll
    for (int r = 0; r < 4; ++r) { best[rt][r] = -INFINITY; bidx[rt][r] = 0; }

  // rotate k start per block to stagger staging phases (tie-rule keeps
  // jnp.argmax first-max semantics order-independent)
  const int rot = (blockIdx.y * 5 + blockIdx.x) & (KLOCAL - 1);

  for (int ki = 0; ki < KLOCAL; ++ki) {
    const int k = ks * KLOCAL + ((ki + rot) & (KLOCAL - 1));

    __syncthreads();
    // stage P_k (hi|lo, padded) linearly into LDS: 1152 x 16 B
    {
      const uint4* s4 = (const uint4*)(Pt + k * PT_K_BYTES);
      for (int i = tid; i < PT_K_BYTES / 16; i += THREADS) lds_p4[i] = s4[i];
    }
    __syncthreads();

    const float ck = cvec[k];
    float sq[2][4] = {{0.f,0.f,0.f,0.f},{0.f,0.f,0.f,0.f}};

#pragma unroll
    for (int et = 0; et < 4; ++et) {
      // acc init: -muP[k][e], e = et*16 + m (same for all 4 row-regs)
      const float mval = -muP[k * DIM + et * 16 + m];
      f32x4 acc[2];
#pragma unroll
      for (int rt = 0; rt < 2; ++rt)
#pragma unroll
        for (int r = 0; r < 4; ++r) acc[rt][r] = mval;

#pragma unroll
      for (int c = 0; c < 2; ++c) {
        // B[k=q*8+j][n = et*16+m] from transposed Pt rows: contiguous b128
        const char* bp = lds_p + (et * 16 + m) * PT_ROW_BYTES + c * 64 + q * 16;
        f16x8 bh = *(const f16x8*)bp;
        f16x8 bl = *(const f16x8*)(bp + PT_SPLIT_BYTES);
#pragma unroll
        for (int rt = 0; rt < 2; ++rt) {
          acc[rt] = __builtin_amdgcn_mfma_f32_16x16x32_f16(ahi[rt][c], bh, acc[rt], 0, 0, 0);
          acc[rt] = __builtin_amdgcn_mfma_f32_16x16x32_f16(ahi[rt][c], bl, acc[rt], 0, 0, 0);
          acc[rt] = __builtin_amdgcn_mfma_f32_16x16x32_f16(alo[rt][c], bh, acc[rt], 0, 0, 0);
        }
      }
#pragma unroll
      for (int rt = 0; rt < 2; ++rt)
#pragma unroll
        for (int r = 0; r < 4; ++r)
          sq[rt][r] = fmaf(acc[rt][r], acc[rt][r], sq[rt][r]);
    }

    // reduce over the 16 e-lanes (lower 4 lane bits), then argmax update
#pragma unroll
    for (int rt = 0; rt < 2; ++rt)
#pragma unroll
      for (int r = 0; r < 4; ++r) {
        float s = sq[rt][r];
        s += __shfl_xor(s, 1);
        s += __shfl_xor(s, 2);
        s += __shfl_xor(s, 4);
        s += __shfl_xor(s, 8);
        float w = fmaf(-0.5f, s, ck);
        if (w > best[rt][r] || (w == best[rt][r] && k < bidx[rt][r])) {
          best[rt][r] = w; bidx[rt][r] = k;
        }
      }
  }

  if (m == 0) {
#pragma unroll
    for (int rt = 0; rt < 2; ++rt)
#pragma unroll
      for (int r = 0; r < 4; ++r) {
        int row = rowbase + rt * 16 + q * 4 + r;
        pval[ks * N_ROWS + row] = best[rt][r];
        pidx[ks * N_ROWS + row] = bidx[rt][r];
      }
  }
}

// ---------------- final reduce over k-splits ----------------
__global__ void reduce_kernel(const float* __restrict__ pval,
                              const int* __restrict__ pidx,
                              int* __restrict__ out)
{
  int n = blockIdx.x * blockDim.x + threadIdx.x;
  if (n >= N_ROWS) return;
  float best = -INFINITY; int bi = 0;
  for (int ks = 0; ks < KSPLIT; ++ks) {
    float v = pval[ks * N_ROWS + n];
    int   i = pidx[ks * N_ROWS + n];
    if (v > best || (v == best && i < bi)) { best = v; bi = i; }
  }
  out[n] = bi;
}

extern "C" void kernel_launch(void* const* d_in, const int* in_sizes, int n_in,
                              void* d_out, int out_size, void* d_ws, size_t ws_size,
                              hipStream_t stream) {
  const float* X     = (const float*)d_in[0];
  const float* means = (const float*)d_in[1];
  const float* P     = (const float*)d_in[2];
  const float* wc    = (const float*)d_in[3];
  const float* dof   = (const float*)d_in[4];
  const float* mp    = (const float*)d_in[5];
  int* out = (int*)d_out;

  // workspace layout (bytes):
  // [0,16384)            muP (4096 f32)
  // [16384,16640)        cvec (64 f32)
  // [16640,17152)        t_arr (64 f64)
  // [17152,17664)        g_arr
  // [17664,18176)        pc_arr
  // [32768, 32768+1179648)  Pt  (64 k * 18432 B)
  // then pval (KSPLIT*N f32), pidx (KSPLIT*N i32)
  char* wsb = (char*)d_ws;
  float*  muP    = (float*)(wsb);
  float*  cvec   = (float*)(wsb + 16384);
  double* t_arr  = (double*)(wsb + 16640);
  double* g_arr  = (double*)(wsb + 17152);
  double* pc_arr = (double*)(wsb + 17664);
  char*   Pt     = wsb + 32768;
  float*  pval   = (float*)(wsb + 32768 + (size_t)KCOMP * PT_K_BYTES);
  int*    pidx   = (int*)(wsb + 32768 + (size_t)KCOMP * PT_K_BYTES
                          + (size_t)KSPLIT * N_ROWS * sizeof(float));

  prep1_kernel<<<KCOMP, 64, 0, stream>>>(means, P, wc, dof, mp, muP, t_arr, g_arr, pc_arr);
  prep2_kernel<<<1, KCOMP, 0, stream>>>(t_arr, g_arr, pc_arr, cvec);
  prepP_kernel<<<KCOMP, THREADS, 0, stream>>>(P, Pt);

  dim3 grid(N_ROWS / ROWS_PER_BLOCK, KSPLIT);
  main_kernel<<<grid, THREADS, 0, stream>>>(X, Pt, muP, cvec, pval, pidx);

  reduce_kernel<<<(N_ROWS + 255) / 256, 256, 0, stream>>>(pval, pidx, out);
}

// Round 5
// 148.786 us; speedup vs baseline: 3.6593x; 1.0071x over previous
//
#include <hip/hip_runtime.h>
#include <math.h>

#define N_ROWS 32768
#define DIM 64
#define KCOMP 64
#define KSPLIT 4
#define KLOCAL 16          // KCOMP / KSPLIT
#define THREADS 256
#define ROWS_PER_BLOCK 128 // 4 waves * 32 rows
#define ROWS_PER_WAVE 32   // 2 row-tiles of 16

// Pt layout per k (16384 B total, no padding):
//   for et in 0..4, c in 0..2:  block of 2048 B at (et*2+c)*2048:
//     [hi: 64 chunks x 16 B, chunk index = lane = q*16+m]
//     [lo: same, +1024]
//   chunk(lane) holds f16 P[d = c*32 + q*8 + j][e = et*16 + m], j=0..7
#define PT_K_BYTES 16384

#define LOG2PI_D 1.8378770664093454836

typedef _Float16 f16x8 __attribute__((ext_vector_type(8)));
typedef float f32x4 __attribute__((ext_vector_type(4)));

// ---------------- digamma (double, recurrence + asymptotic) ----------------
__device__ __forceinline__ double digamma_d(double x) {
  double r = 0.0;
  while (x < 6.0) { r -= 1.0 / x; x += 1.0; }
  double inv = 1.0 / x;
  double inv2 = inv * inv;
  double s = log(x) - 0.5 * inv
      - inv2 * (1.0/12.0 - inv2 * (1.0/120.0 - inv2 * (1.0/252.0
      - inv2 * (1.0/240.0 - inv2 * (1.0/132.0)))));
  return r + s;
}

// ------- prep1: one block per k. All 256 threads: repack P into Pt.
//         Wave 0: muP, log-det, digamma sums, stick-breaking terms. -------
__global__ void prep1_kernel(const float* __restrict__ means,
                             const float* __restrict__ P,
                             const float* __restrict__ wc,
                             const float* __restrict__ dof,
                             const float* __restrict__ mp,
                             char*   __restrict__ Pt,
                             float*  __restrict__ muP,
                             double* __restrict__ t_arr,
                             double* __restrict__ g_arr,
                             double* __restrict__ pc_arr)
{
  const int k = blockIdx.x;
  const int t = threadIdx.x;
  const float* Pk = P + k * DIM * DIM;

  // ---- repack + f16-split: 8192 f16 per k, 32 consecutive per thread ----
  _Float16* dst = (_Float16*)(Pt + (size_t)k * PT_K_BYTES);
#pragma unroll 4
  for (int u = 0; u < 32; ++u) {
    int o = t * 32 + u;                 // f16 index in [0, 8192)
    int blk    = o >> 10;               // (et*2 + c)
    int within = o & 1023;
    int sel  = within >> 9;             // 0=hi 1=lo
    int lane = (within >> 3) & 63;
    int j    = o & 7;
    int et = blk >> 1, c = blk & 1;
    int m = lane & 15, q = lane >> 4;
    int d = c * 32 + q * 8 + j;
    int e = et * 16 + m;
    float v = Pk[d * DIM + e];
    _Float16 h = (_Float16)v;
    dst[o] = sel ? (_Float16)(v - (float)h) : h;
  }

  if (t < 64) {
    const int i = t;                    // 0..63, exactly wave 0
    const float* mk = means + k * DIM;
    float acc = 0.f;
#pragma unroll 8
    for (int d = 0; d < DIM; ++d) acc = fmaf(mk[d], Pk[d * DIM + i], acc);
    muP[k * DIM + i] = acc;

    double dofk = (double)dof[k];
    double s1 = digamma_d(0.5 * (dofk - (double)i));
    double s2 = log((double)Pk[i * DIM + i]);
#pragma unroll
    for (int off = 32; off > 0; off >>= 1) {
      s1 += __shfl_down(s1, off);
      s2 += __shfl_down(s2, off);
    }
    if (i == 0) {
      double ak = (double)wc[k], bk = (double)wc[KCOMP + k];
      double dgab = digamma_d(ak + bk);
      double log_lambda = (double)DIM * log(2.0) + s1;
      double pc = s2
                - 0.5 * (double)DIM * LOG2PI_D
                - 0.5 * (double)DIM * log(dofk)
                + 0.5 * (log_lambda - (double)DIM / (double)mp[k]);
      t_arr[k] = digamma_d(bk) - dgab;
      g_arr[k] = digamma_d(ak) - dgab;
      pc_arr[k] = pc;
    }
  }
}

// ---------------- prep2: stick-breaking prefix + final cvec ----------------
__global__ void prep2_kernel(const double* __restrict__ t_arr,
                             const double* __restrict__ g_arr,
                             const double* __restrict__ pc_arr,
                             float* __restrict__ cvec)
{
  const int k = threadIdx.x;
  double cum = 0.0;
  for (int j = 0; j < k; ++j) cum += t_arr[j];
  cvec[k] = (float)(pc_arr[k] + g_arr[k] + cum);
}

// -------- main: f16-split MFMA, B-frags straight from L2, no LDS --------
__global__ __launch_bounds__(THREADS, 4) void main_kernel(
    const float* __restrict__ X,
    const char*  __restrict__ Pt,
    const float* __restrict__ muP,
    const float* __restrict__ cvec,
    float* __restrict__ pval,   // [KSPLIT][N_ROWS]
    int*   __restrict__ pidx)
{
  const int tid  = threadIdx.x;
  const int wave = tid >> 6;
  const int lane = tid & 63;
  const int m    = lane & 15;          // MFMA row (A) / col (B) index
  const int q    = lane >> 4;          // quad
  const int ks   = blockIdx.y;
  const int rowbase = blockIdx.x * ROWS_PER_BLOCK + wave * ROWS_PER_WAVE;

  // ---- load + split X rows into register-resident A fragments ----
  // A[m=lane&15][k_local = q*8 + j], chain c covers d = c*32 .. c*32+31
  f16x8 ahi[2][2], alo[2][2];
#pragma unroll
  for (int rt = 0; rt < 2; ++rt) {
    int row = rowbase + rt * 16 + m;
    const float* xp = X + row * DIM;
#pragma unroll
    for (int c = 0; c < 2; ++c) {
      const float4* xq4 = (const float4*)(xp + c * 32 + q * 8);
      float4 v0 = xq4[0], v1 = xq4[1];
      float xv[8] = {v0.x, v0.y, v0.z, v0.w, v1.x, v1.y, v1.z, v1.w};
      f16x8 h, l;
#pragma unroll
      for (int j = 0; j < 8; ++j) {
        _Float16 hv = (_Float16)xv[j];
        h[j] = hv;
        l[j] = (_Float16)(xv[j] - (float)hv);
      }
      ahi[rt][c] = h;
      alo[rt][c] = l;
    }
  }

  float best[2][4];
  int   bidx[2][4];
#pragma unroll
  for (int rt = 0; rt < 2; ++rt)
#pragma unroll
    for (int r = 0; r < 4; ++r) { best[rt][r] = -INFINITY; bidx[rt][r] = 0; }

  for (int ki = 0; ki < KLOCAL; ++ki) {
    const int k = ks * KLOCAL + ki;
    const char* pk = Pt + (size_t)k * PT_K_BYTES;
    const float ck = cvec[k];
    float sq[2][4] = {{0.f,0.f,0.f,0.f},{0.f,0.f,0.f,0.f}};

#pragma unroll
    for (int et = 0; et < 4; ++et) {
      const float mval = -muP[k * DIM + et * 16 + m];
      f32x4 acc[2];
#pragma unroll
      for (int rt = 0; rt < 2; ++rt)
#pragma unroll
        for (int r = 0; r < 4; ++r) acc[rt][r] = mval;

#pragma unroll
      for (int c = 0; c < 2; ++c) {
        const char* bp = pk + ((et * 2 + c) << 11) + (lane << 4);
        f16x8 bh = *(const f16x8*)bp;            // coalesced 1 KB per wave
        f16x8 bl = *(const f16x8*)(bp + 1024);
#pragma unroll
        for (int rt = 0; rt < 2; ++rt) {
          acc[rt] = __builtin_amdgcn_mfma_f32_16x16x32_f16(ahi[rt][c], bh, acc[rt], 0, 0, 0);
          acc[rt] = __builtin_amdgcn_mfma_f32_16x16x32_f16(ahi[rt][c], bl, acc[rt], 0, 0, 0);
          acc[rt] = __builtin_amdgcn_mfma_f32_16x16x32_f16(alo[rt][c], bh, acc[rt], 0, 0, 0);
        }
      }
#pragma unroll
      for (int rt = 0; rt < 2; ++rt)
#pragma unroll
        for (int r = 0; r < 4; ++r)
          sq[rt][r] = fmaf(acc[rt][r], acc[rt][r], sq[rt][r]);
    }

    // reduce over the 16 e-lanes (lower 4 lane bits), then argmax update
#pragma unroll
    for (int rt = 0; rt < 2; ++rt)
#pragma unroll
      for (int r = 0; r < 4; ++r) {
        float s = sq[rt][r];
        s += __shfl_xor(s, 1);
        s += __shfl_xor(s, 2);
        s += __shfl_xor(s, 4);
        s += __shfl_xor(s, 8);
        float w = fmaf(-0.5f, s, ck);
        if (w > best[rt][r] || (w == best[rt][r] && k < bidx[rt][r])) {
          best[rt][r] = w; bidx[rt][r] = k;
        }
      }
  }

  if (m == 0) {
#pragma unroll
    for (int rt = 0; rt < 2; ++rt)
#pragma unroll
      for (int r = 0; r < 4; ++r) {
        int row = rowbase + rt * 16 + q * 4 + r;
        pval[ks * N_ROWS + row] = best[rt][r];
        pidx[ks * N_ROWS + row] = bidx[rt][r];
      }
  }
}

// ---------------- final reduce over k-splits ----------------
__global__ void reduce_kernel(const float* __restrict__ pval,
                              const int* __restrict__ pidx,
                              int* __restrict__ out)
{
  int n = blockIdx.x * blockDim.x + threadIdx.x;
  if (n >= N_ROWS) return;
  float best = -INFINITY; int bi = 0;
  for (int ks = 0; ks < KSPLIT; ++ks) {
    float v = pval[ks * N_ROWS + n];
    int   i = pidx[ks * N_ROWS + n];
    if (v > best || (v == best && i < bi)) { best = v; bi = i; }
  }
  out[n] = bi;
}

extern "C" void kernel_launch(void* const* d_in, const int* in_sizes, int n_in,
                              void* d_out, int out_size, void* d_ws, size_t ws_size,
                              hipStream_t stream) {
  const float* X     = (const float*)d_in[0];
  const float* means = (const float*)d_in[1];
  const float* P     = (const float*)d_in[2];
  const float* wc    = (const float*)d_in[3];
  const float* dof   = (const float*)d_in[4];
  const float* mp    = (const float*)d_in[5];
  int* out = (int*)d_out;

  // workspace layout (bytes):
  // [0,16384)           muP (4096 f32)
  // [16384,16640)       cvec (64 f32)
  // [16640,17152)       t_arr (64 f64)
  // [17152,17664)       g_arr
  // [17664,18176)       pc_arr
  // [32768, 32768+1048576)  Pt (64 k * 16384 B)
  // then pval (KSPLIT*N f32), pidx (KSPLIT*N i32)
  char* wsb = (char*)d_ws;
  float*  muP    = (float*)(wsb);
  float*  cvec   = (float*)(wsb + 16384);
  double* t_arr  = (double*)(wsb + 16640);
  double* g_arr  = (double*)(wsb + 17152);
  double* pc_arr = (double*)(wsb + 17664);
  char*   Pt     = wsb + 32768;
  float*  pval   = (float*)(wsb + 32768 + (size_t)KCOMP * PT_K_BYTES);
  int*    pidx   = (int*)(wsb + 32768 + (size_t)KCOMP * PT_K_BYTES
                          + (size_t)KSPLIT * N_ROWS * sizeof(float));

  prep1_kernel<<<KCOMP, THREADS, 0, stream>>>(means, P, wc, dof, mp, Pt,
                                              muP, t_arr, g_arr, pc_arr);
  prep2_kernel<<<1, KCOMP, 0, stream>>>(t_arr, g_arr, pc_arr, cvec);

  dim3 grid(N_ROWS / ROWS_PER_BLOCK, KSPLIT);
  main_kernel<<<grid, THREADS, 0, stream>>>(X, Pt, muP, cvec, pval, pidx);

  reduce_kernel<<<(N_ROWS + 255) / 256, 256, 0, stream>>>(pval, pidx, out);
}